// Round 1
// 137.215 us; speedup vs baseline: 1.3390x; 1.3390x over previous
//
#include <hip/hip_runtime.h>
#include <hip/hip_bf16.h>

#define EPS 1e-5f

constexpr int BB   = 64;    // batch
constexpr int CDIM = 448;
constexpr int PD   = 96;    // PDIM
constexpr int QKD  = 16;    // QK
constexpr int QO   = 128;   // 2*QK + PDIM
constexpr int NPix = 1024;  // H*W
constexpr int NCH  = 14;    // 448 / 32 chunks

// ---- workspace layout (float offsets) ----
constexpr size_t WS_MU  = 0;        // [64]
constexpr size_t WS_RS  = 64;       // [64]
constexpr size_t WS_QSC = 128;      // [128]
constexpr size_t WS_QBI = 256;      // [128]
constexpr size_t WS_PSC = 384;      // [448]
constexpr size_t WS_PBI = 832;      // [448]
constexpr size_t WS_WG  = 1280;     // [128*96] (unused legacy slot)
constexpr size_t WS_SWG = 13568;    // [128]
constexpr size_t WS_WB  = 13696;    // [128]
constexpr size_t WS_WGT = 13824;    // [96*128] (unused legacy slot)
constexpr size_t WS_WGH = 26112;    // ushort[128][96] f16 Wg (6144 floats)
constexpr size_t WS_YB  = 32768;                                  // ushort[64][14][1024][32] chunked proj input
constexpr size_t WS_W16 = WS_YB + (size_t)BB*NPix*CDIM/2;         // ushort[512*448] bf16 proj W
constexpr size_t WS_QT  = WS_W16 + (size_t)512*CDIM/2;            // ushort f16 [64][1024][32]
constexpr size_t WS_KT  = WS_QT + (size_t)BB*NPix*32/2;           // ushort f16 [64][1024][32]
constexpr size_t WS_VB  = WS_KT + (size_t)BB*NPix*32/2;           // ushort f16 [64][96][1024]

typedef __attribute__((ext_vector_type(8))) short short8;
typedef __attribute__((ext_vector_type(8))) _Float16 half8;
typedef __attribute__((ext_vector_type(4))) float f32x4;

__device__ __forceinline__ unsigned short f2bf(float v) {
  __hip_bfloat16 h = __float2bfloat16(v);
  return *reinterpret_cast<unsigned short*>(&h);
}
__device__ __forceinline__ unsigned short f2h(float v) {
  _Float16 h = (_Float16)v;
  return *reinterpret_cast<unsigned short*>(&h);
}

typedef const __attribute__((address_space(1))) unsigned int* gp_t;
typedef __attribute__((address_space(3))) unsigned int* lp_t;
__device__ __forceinline__ void gload16(const void* g, void* l) {
  __builtin_amdgcn_global_load_lds((gp_t)g, (lp_t)l, 16, 0, 0);
}

// ---------------- kernel 1: fused setup + x2 passthrough (chunked full-line) --------
// REORDERED: low-parallelism tail blocks dispatch FIRST (blocks 0..208) so they
// overlap the 11264-block XT phase instead of running serially after it.
//   blocks [0,64):    GN stats (unrolled, 8 loads in flight)
//   blocks [64,96):   weight fold, one wave per output row o (lane-par over c)
//   block  96:        proj BN scale/bias folds
//   blocks [97,209):  proj W -> bf16
//   blocks [209, +11264): xt -> Ybc[b][3+cy][n][32]
constexpr int XT_BLOCKS = 11264;
constexpr int TAILB     = 209;
__global__ __launch_bounds__(256) void k_setup(
    const float* __restrict__ x,
    const float* __restrict__ gn_w, const float* __restrict__ gn_b,
    const float* __restrict__ qkv_w,
    const float* __restrict__ qbw, const float* __restrict__ qbb,
    const float* __restrict__ qbrm, const float* __restrict__ qbrv,
    const float* __restrict__ pw,
    const float* __restrict__ pbw, const float* __restrict__ pbb,
    const float* __restrict__ pbrm, const float* __restrict__ pbrv,
    float* __restrict__ ws, unsigned short* __restrict__ Wb,
    unsigned short* __restrict__ Ybc) {
  __shared__ float tile[32][65];   // 8.3 KB; also covers red[8]
  float* red = &tile[0][0];
  int t = threadIdx.x;
  if (blockIdx.x >= TAILB) {
    int idx = blockIdx.x - TAILB;
    int nx = idx & 15, cy = (idx >> 4) % 11, b = idx / 176;
    int c0 = PD + cy * 32;
    int n0 = nx * 64;
#pragma unroll
    for (int i = 0; i < 2; ++i) {
      int k = t + i * 256;
      int c = k >> 4, q = k & 15;
      float4 v = reinterpret_cast<const float4*>(
                     x + ((size_t)b * CDIM + c0 + c) * NPix + n0)[q];
      *reinterpret_cast<float4*>(&tile[c][q * 4]) = v;
    }
    __syncthreads();
    int n = t >> 2, ch = t & 3;
    short8 o;
#pragma unroll
    for (int j = 0; j < 8; ++j)
      o[j] = (short)f2bf(fmaxf(tile[ch * 8 + j][n], 0.f));
    *reinterpret_cast<short8*>(
        &Ybc[(((size_t)b * NCH + 3 + cy) * NPix + n0 + n) * 32 + ch * 8]) = o;
    return;
  }
  int bid = blockIdx.x;
  if (bid < 64) {
    int b = bid;
    const float4* x4 = reinterpret_cast<const float4*>(x + (size_t)b * CDIM * NPix);
    float s = 0.f, ss = 0.f;
#pragma unroll 8
    for (int ii = 0; ii < PD * NPix / 4 / 256; ++ii) {
      float4 v = x4[t + ii * 256];
      s  += v.x + v.y + v.z + v.w;
      ss += v.x * v.x + v.y * v.y + v.z * v.z + v.w * v.w;
    }
#pragma unroll
    for (int o = 32; o > 0; o >>= 1) { s += __shfl_down(s, o); ss += __shfl_down(ss, o); }
    int wid = t >> 6;
    if ((t & 63) == 0) { red[wid] = s; red[4 + wid] = ss; }
    __syncthreads();
    if (t == 0) {
      float S  = red[0] + red[1] + red[2] + red[3];
      float SS = red[4] + red[5] + red[6] + red[7];
      const float inv_n = 1.f / (PD * NPix);
      float mu  = S * inv_n;
      float var = SS * inv_n - mu * mu;
      ws[WS_MU + b] = mu;
      ws[WS_RS + b] = rsqrtf(var + EPS);
    }
  } else if (bid < 96) {
    // fold: one wave per output row o, lanes parallel over c (coalesced)
    int o = (bid - 64) * 4 + (t >> 6);
    int lane = t & 63;
    unsigned short* Wgh = reinterpret_cast<unsigned short*>(ws + WS_WGH);
    float sw = 0.f, bb = 0.f;
    for (int c = lane; c < PD; c += 64) {
      float w  = qkv_w[o * PD + c];
      float wg = w * gn_w[c];
      Wgh[(size_t)o * PD + c] = f2h(wg);
      sw += wg;
      bb += w * gn_b[c];
    }
#pragma unroll
    for (int off = 32; off > 0; off >>= 1) {
      sw += __shfl_down(sw, off);
      bb += __shfl_down(bb, off);
    }
    if (lane == 0) {
      ws[WS_SWG + o] = sw;
      ws[WS_WB + o]  = bb;
      float sc = qbw[o] * rsqrtf(qbrv[o] + EPS);
      ws[WS_QSC + o] = sc;
      ws[WS_QBI + o] = qbb[o] - qbrm[o] * sc;
    }
  } else if (bid == 96) {
    for (int o = t; o < CDIM; o += 256) {
      float sc = pbw[o] * rsqrtf(pbrv[o] + EPS);
      ws[WS_PSC + o] = sc;
      ws[WS_PBI + o] = pbb[o] - pbrm[o] * sc;
    }
  } else {
    int idx = (bid - 97) * 256 + t;   // 512*448/8 = 28672 chunks
    int row = idx / 56, sl = (idx % 56) * 8;
    short8 o = {};
    if (row < CDIM) {
      const float* src = pw + (size_t)row * CDIM + sl;
#pragma unroll
      for (int j = 0; j < 8; ++j) o[j] = (short)f2bf(src[j]);
    }
    *reinterpret_cast<short8*>(&Wb[(size_t)row * CDIM + sl]) = o;
  }
}

// ---------------- kernel 2: qkv via f16 MFMA + BN + operand emit ----------------
// acc[o][n] = mfma(Wgh rows [o][c], x^T rows [n][c]) over K=96 (3 x 32).
// B-frags built by transpose-read of the f32 xt tile (cvt f16 in regs).
// Epilogue (BN + 0.25 q-fold) -> ld union -> unchanged qt/kt/vb emits.
__global__ __launch_bounds__(256) void k_qkv2(const float* __restrict__ x,
                                              float* __restrict__ ws,
                                              unsigned short* __restrict__ qt,
                                              unsigned short* __restrict__ kt,
                                              unsigned short* __restrict__ vb) {
  __shared__ __align__(16) char smem[PD * 132 * 4];     // 50688 B union
  float*          xt = reinterpret_cast<float*>(smem);          // [96][132] f32
  unsigned short* ld = reinterpret_cast<unsigned short*>(smem); // [128][136] f16

  int lin = blockIdx.x + 8 * blockIdx.y;          // 512 wgs, chunked XCD swizzle
  int swz = (lin & 7) * 64 + (lin >> 3);
  int n0  = (swz & 7) * 128;
  int b   = swz >> 3;
  int t   = threadIdx.x;
  int lane = t & 63, w = t >> 6;
  int lo = lane & 15, hi = lane >> 4;

  const float4* xb4 = reinterpret_cast<const float4*>(x + (size_t)b * CDIM * NPix);
#pragma unroll
  for (int i = 0; i < 12; ++i) {                  // stage x1 tile [96][128]
    int idx = t + i * 256;
    int row = idx >> 5, c4 = idx & 31;
    float4 v = xb4[row * (NPix / 4) + (n0 >> 2) + c4];
    *reinterpret_cast<float4*>(&xt[row * 132 + c4 * 4]) = v;
  }
  __syncthreads();

  const unsigned short* Wgh = reinterpret_cast<const unsigned short*>(ws + WS_WGH);
  f32x4 acc[8][2] = {{{}}};
#pragma unroll
  for (int kk = 0; kk < 3; ++kk) {
    half8 bfr[2];
#pragma unroll
    for (int nf = 0; nf < 2; ++nf) {
      int nr = w * 32 + nf * 16 + lo;
      half8 h;
#pragma unroll
      for (int j = 0; j < 8; ++j)
        h[j] = (_Float16)xt[(kk * 32 + hi * 8 + j) * 132 + nr];
      bfr[nf] = h;
    }
#pragma unroll
    for (int of = 0; of < 8; ++of) {
      half8 a = *reinterpret_cast<const half8*>(
          &Wgh[(size_t)(of * 16 + lo) * PD + kk * 32 + hi * 8]);
      acc[of][0] = __builtin_amdgcn_mfma_f32_16x16x32_f16(a, bfr[0], acc[of][0], 0, 0, 0);
      acc[of][1] = __builtin_amdgcn_mfma_f32_16x16x32_f16(a, bfr[1], acc[of][1], 0, 0, 0);
    }
  }
  float mu = ws[WS_MU + b], rs = ws[WS_RS + b];
  __syncthreads();     // all xt reads done; smem becomes ld
#pragma unroll
  for (int of = 0; of < 8; ++of) {
#pragma unroll
    for (int r = 0; r < 4; ++r) {
      int o = of * 16 + hi * 4 + r;
      float bias = ws[WS_WB + o] - rs * mu * ws[WS_SWG + o];
      float qs = ws[WS_QSC + o], qb = ws[WS_QBI + o];
      float postm = (o < QKD) ? 0.25f : 1.f;
#pragma unroll
      for (int nf = 0; nf < 2; ++nf) {
        int nl = w * 32 + nf * 16 + lo;
        float v = (qs * (rs * acc[of][nf][r] + bias) + qb) * postm;
        ld[o * 136 + nl] = f2h(v);
      }
    }
  }
  __syncthreads();
  // ---- emit vb: rows o=32..127 -> c=0..95 ----
#pragma unroll
  for (int i = 0; i < 6; ++i) {
    int idx = t + i * 256;
    int row = idx >> 4, c8 = idx & 15;
    short8 v = *reinterpret_cast<const short8*>(&ld[(32 + row) * 136 + c8 * 8]);
    *reinterpret_cast<short8*>(&vb[((size_t)b * PD + row) * NPix + n0 + c8 * 8]) = v;
  }
  // ---- emit qt/kt: transposed gather, zero-padded to 32 ch ----
#pragma unroll
  for (int i = 0; i < 4; ++i) {
    int idx = t + i * 256;
    int arr = idx >> 9;
    int rem = idx & 511;
    int n = rem >> 2, q4 = rem & 3;
    short8 o = {};
    if (q4 < 2) {
#pragma unroll
      for (int j = 0; j < 8; ++j)
        o[j] = (short)ld[(arr * 16 + q4 * 8 + j) * 136 + n];
    }
    unsigned short* dst = arr ? kt : qt;
    *reinterpret_cast<short8*>(&dst[((size_t)b * NPix + n0 + n) * 32 + q4 * 8]) = o;
  }
}

// ---------------- kernel 3: flash attention via f16 MFMA -> Ybc chunks 0..2 ---------
__global__ __launch_bounds__(512) void k_attn2(
    const unsigned short* __restrict__ qt,
    const unsigned short* __restrict__ kt,
    const unsigned short* __restrict__ vb,
    unsigned short* __restrict__ Ybc) {
  __shared__ __align__(16) unsigned short kt_s[128 * 40];
  __shared__ __align__(16) unsigned short vt_s[96 * 136];
  __shared__ __align__(16) unsigned short P_s[8 * 16 * 136];

  int lin = blockIdx.x + 8 * blockIdx.y;
  int swz = (lin & 7) * 64 + (lin >> 3);
  int n0  = (swz & 7) * 128;
  int b   = swz >> 3;
  int t  = threadIdx.x;
  int lane = t & 63, w = t >> 6;
  int lo = lane & 15, hi = lane >> 4;

  half8 q8 = *reinterpret_cast<const half8*>(
      &qt[((size_t)b * NPix + n0 + w * 16 + lo) * 32 + hi * 8]);

  const unsigned short* ktb = kt + (size_t)b * NPix * 32;
  const unsigned short* vbb = vb + (size_t)b * PD * NPix;

  f32x4 o[6] = {};
  float M = -1e30f, L = 0.f;
  f32x4 zero = {};

  for (int mt = 0; mt < 8; ++mt) {
    int m0 = mt * 128;
    int krow = t >> 2, kc4 = t & 3;
    float4 rk = *reinterpret_cast<const float4*>(&ktb[(size_t)(m0 + krow) * 32 + kc4 * 8]);
    float4 rv[3];
#pragma unroll
    for (int i = 0; i < 3; ++i) {
      int ci = t + 512 * i;
      int row = ci >> 4, c4 = ci & 15;
      rv[i] = *reinterpret_cast<const float4*>(&vbb[(size_t)row * NPix + m0 + c4 * 8]);
    }
    __syncthreads();
    *reinterpret_cast<float4*>(&kt_s[krow * 40 + kc4 * 8]) = rk;
#pragma unroll
    for (int i = 0; i < 3; ++i) {
      int ci = t + 512 * i;
      int row = ci >> 4, c4 = ci & 15;
      *reinterpret_cast<float4*>(&vt_s[row * 136 + c4 * 8]) = rv[i];
    }
    __syncthreads();

    f32x4 s[8];
    __builtin_amdgcn_s_setprio(1);
#pragma unroll
    for (int ss = 0; ss < 8; ++ss) {
      half8 a = *reinterpret_cast<const half8*>(&kt_s[(ss * 16 + lo) * 40 + hi * 8]);
      s[ss] = __builtin_amdgcn_mfma_f32_16x16x32_f16(a, q8, zero, 0, 0, 0);
    }
    __builtin_amdgcn_s_setprio(0);

    float tmax = s[0][0];
#pragma unroll
    for (int ss = 0; ss < 8; ++ss)
#pragma unroll
      for (int r = 0; r < 4; ++r) tmax = fmaxf(tmax, s[ss][r]);
    tmax = fmaxf(tmax, __shfl_xor(tmax, 16));
    tmax = fmaxf(tmax, __shfl_xor(tmax, 32));
    float newM = fmaxf(M, tmax);
    float fac = __expf(M - newM);
    M = newM;
    float psum = 0.f;
    unsigned pbase = (w * 16 + lo) * 136;
#pragma unroll
    for (int ss = 0; ss < 8; ++ss) {
      float p0 = __expf(s[ss][0] - M);
      float p1 = __expf(s[ss][1] - M);
      float p2 = __expf(s[ss][2] - M);
      float p3 = __expf(s[ss][3] - M);
      psum += (p0 + p1) + (p2 + p3);
      unsigned u01 = (unsigned)f2h(p0) | ((unsigned)f2h(p1) << 16);
      unsigned u23 = (unsigned)f2h(p2) | ((unsigned)f2h(p3) << 16);
      *reinterpret_cast<unsigned*>(&P_s[pbase + 16 * ss + 4 * hi])     = u01;
      *reinterpret_cast<unsigned*>(&P_s[pbase + 16 * ss + 4 * hi + 2]) = u23;
    }
    psum += __shfl_xor(psum, 16);
    psum += __shfl_xor(psum, 32);
    L = L * fac + psum;
#pragma unroll
    for (int cf = 0; cf < 6; ++cf)
#pragma unroll
      for (int r = 0; r < 4; ++r) o[cf][r] *= fac;
    asm volatile("s_waitcnt lgkmcnt(0)" ::: "memory");

    __builtin_amdgcn_s_setprio(1);
#pragma unroll
    for (int ks = 0; ks < 4; ++ks) {
      half8 pb = *reinterpret_cast<const half8*>(&P_s[pbase + ks * 32 + hi * 8]);
#pragma unroll
      for (int cf = 0; cf < 6; ++cf) {
        half8 va = *reinterpret_cast<const half8*>(&vt_s[(cf * 16 + lo) * 136 + ks * 32 + hi * 8]);
        o[cf] = __builtin_amdgcn_mfma_f32_16x16x32_f16(va, pb, o[cf], 0, 0, 0);
      }
    }
    __builtin_amdgcn_s_setprio(0);
  }

  float inv = 1.f / L;
  unsigned pbase = (w * 16 + lo) * 136;
#pragma unroll
  for (int cf = 0; cf < 6; ++cf) {
    float v0 = fmaxf(o[cf][0] * inv, 0.f);
    float v1 = fmaxf(o[cf][1] * inv, 0.f);
    float v2 = fmaxf(o[cf][2] * inv, 0.f);
    float v3 = fmaxf(o[cf][3] * inv, 0.f);
    unsigned u01 = (unsigned)f2bf(v0) | ((unsigned)f2bf(v1) << 16);
    unsigned u23 = (unsigned)f2bf(v2) | ((unsigned)f2bf(v3) << 16);
    *reinterpret_cast<unsigned*>(&P_s[pbase + cf * 16 + 4 * hi])     = u01;
    *reinterpret_cast<unsigned*>(&P_s[pbase + cf * 16 + 4 * hi + 2]) = u23;
  }
  asm volatile("s_waitcnt lgkmcnt(0)" ::: "memory");
#pragma unroll
  for (int j = 0; j < 3; ++j) {
    int k = lane + 64 * j;
    int n = k / 12, c8 = k % 12;
    short8 vv = *reinterpret_cast<const short8*>(&P_s[(w * 16 + n) * 136 + c8 * 8]);
    *reinterpret_cast<short8*>(
        &Ybc[(((size_t)b * NCH + (c8 >> 2)) * NPix + n0 + w * 16 + n) * 32
             + (c8 & 3) * 8]) = vv;
  }
}

// ---------------- kernel 4: proj GEMM, 3-buffer counted-vmcnt, chunked B ---------
__global__ __launch_bounds__(256) void k_projmm(
    const unsigned short* __restrict__ Wb,    // [512][448] bf16
    const unsigned short* __restrict__ Ybc,   // [64][14][1024][32] bf16
    const float* __restrict__ ws,
    float* __restrict__ out) {
  __shared__ __align__(16) unsigned short At[3][128 * 32];   // 24 KB
  __shared__ __align__(16) unsigned short Bt[3][128 * 32];   // 24 KB
  int lin = blockIdx.x + 8 * (blockIdx.y + 4 * blockIdx.z);  // 2048 wgs
  int swz = (lin & 7) * 256 + (lin >> 3);                    // chunked XCD swizzle
  int m0  = (swz & 3) * 128;         // m0 fastest: 4 m0-blocks of (b,n0) share XCD L2
  int n0  = ((swz >> 2) & 7) * 128;
  int b   = swz >> 5;
  int t  = threadIdx.x;
  int lane = t & 63, wid = t >> 6;
  int wm = wid >> 1, wn = wid & 1;

  const unsigned short* Arow = Wb + (size_t)m0 * CDIM;
  const unsigned short* Brow = Ybc + ((size_t)b * NCH * NPix + n0) * 32;

  int chunk0 = wid * 128 + lane;
  int row0 = chunk0 >> 2, sl0 = (chunk0 & 3) ^ ((row0 >> 1) & 3);
  int chunk1 = chunk0 + 64;
  int row1 = chunk1 >> 2, sl1 = (chunk1 & 3) ^ ((row1 >> 1) & 3);

#define STAGE(bufi, s_)                                                        \
  do {                                                                         \
    gload16(Arow + (size_t)row0 * CDIM + (s_) * 32 + sl0 * 8,                  \
            &At[bufi][(wid * 128) * 8]);                                       \
    gload16(Arow + (size_t)row1 * CDIM + (s_) * 32 + sl1 * 8,                  \
            &At[bufi][(wid * 128 + 64) * 8]);                                  \
    gload16(Brow + (size_t)(s_) * NPix * 32 + row0 * 32 + sl0 * 8,             \
            &Bt[bufi][(wid * 128) * 8]);                                       \
    gload16(Brow + (size_t)(s_) * NPix * 32 + row1 * 32 + sl1 * 8,             \
            &Bt[bufi][(wid * 128 + 64) * 8]);                                  \
  } while (0)

  f32x4 acc[4][4] = {{{}}};

  STAGE(0, 0);
  STAGE(1, 1);
  asm volatile("s_waitcnt vmcnt(4) lgkmcnt(0)" ::: "memory");
  __builtin_amdgcn_sched_barrier(0);
  __builtin_amdgcn_s_barrier();

#pragma unroll
  for (int s = 0; s < 14; ++s) {
    if (s + 2 <= 13) STAGE((s + 2) % 3, s + 2);
    short8 af[4], bfr[4];
#pragma unroll
    for (int f = 0; f < 4; ++f) {
      int ar = wm * 64 + f * 16 + (lane & 15);
      int as = (lane >> 4) ^ ((ar >> 1) & 3);
      af[f] = *reinterpret_cast<const short8*>(&At[s % 3][ar * 32 + as * 8]);
      int br = wn * 64 + f * 16 + (lane & 15);
      int bs = (lane >> 4) ^ ((br >> 1) & 3);
      bfr[f] = *reinterpret_cast<const short8*>(&Bt[s % 3][br * 32 + bs * 8]);
    }
#pragma unroll
    for (int i = 0; i < 4; ++i)
#pragma unroll
      for (int j = 0; j < 4; ++j)
        acc[i][j] = __builtin_amdgcn_mfma_f32_16x16x32_bf16(af[i], bfr[j], acc[i][j], 0, 0, 0);
    if (s < 13) {
      if (s <= 11) asm volatile("s_waitcnt vmcnt(4) lgkmcnt(0)" ::: "memory");
      else         asm volatile("s_waitcnt vmcnt(0) lgkmcnt(0)" ::: "memory");
      __builtin_amdgcn_sched_barrier(0);
      __builtin_amdgcn_s_barrier();
    }
  }
#undef STAGE

  int col = lane & 15, rq = lane >> 4;
#pragma unroll
  for (int i = 0; i < 4; ++i) {
    int ob = m0 + wm * 64 + i * 16 + rq * 4;
#pragma unroll
    for (int r = 0; r < 4; ++r) {
      int o = ob + r;
      if (o < CDIM) {
        float ps = ws[WS_PSC + o], pb = ws[WS_PBI + o];
        size_t base = ((size_t)b * CDIM + o) * NPix + n0 + wn * 64 + col;
#pragma unroll
        for (int j = 0; j < 4; ++j)
          out[base + j * 16] = ps * acc[i][j][r] + pb;
      }
    }
  }
}

extern "C" void kernel_launch(void* const* d_in, const int* in_sizes, int n_in,
                              void* d_out, int out_size, void* d_ws, size_t ws_size,
                              hipStream_t stream) {
  const float* x      = (const float*)d_in[0];
  const float* gn_w   = (const float*)d_in[1];
  const float* gn_b   = (const float*)d_in[2];
  const float* qkv_w  = (const float*)d_in[3];
  const float* qbw    = (const float*)d_in[4];
  const float* qbb    = (const float*)d_in[5];
  const float* qbrm   = (const float*)d_in[6];
  const float* qbrv   = (const float*)d_in[7];
  const float* pw     = (const float*)d_in[8];
  const float* pbw    = (const float*)d_in[9];
  const float* pbb    = (const float*)d_in[10];
  const float* pbrm   = (const float*)d_in[11];
  const float* pbrv   = (const float*)d_in[12];
  float* out = (float*)d_out;
  float* ws  = (float*)d_ws;
  unsigned short* Ybc = (unsigned short*)(ws + WS_YB);
  unsigned short* Wb  = (unsigned short*)(ws + WS_W16);
  unsigned short* qt  = (unsigned short*)(ws + WS_QT);
  unsigned short* kt  = (unsigned short*)(ws + WS_KT);
  unsigned short* vb  = (unsigned short*)(ws + WS_VB);

  k_setup<<<TAILB + XT_BLOCKS, 256, 0, stream>>>(
      x, gn_w, gn_b, qkv_w, qbw, qbb, qbrm, qbrv,
      pw, pbw, pbb, pbrm, pbrv, ws, Wb, Ybc);
  k_qkv2<<<dim3(8, BB), 256, 0, stream>>>(x, ws, qt, kt, vb);
  k_attn2<<<dim3(8, BB), 512, 0, stream>>>(qt, kt, vb, Ybc);
  k_projmm<<<dim3(8, 4, BB), 256, 0, stream>>>(Wb, Ybc, ws, out);
}

// Round 2
// 135.542 us; speedup vs baseline: 1.3555x; 1.0123x over previous
//
#include <hip/hip_runtime.h>
#include <hip/hip_bf16.h>

#define EPS 1e-5f

constexpr int BB   = 64;    // batch
constexpr int CDIM = 448;
constexpr int PD   = 96;    // PDIM
constexpr int QKD  = 16;    // QK
constexpr int QO   = 128;   // 2*QK + PDIM
constexpr int NPix = 1024;  // H*W
constexpr int NCH  = 14;    // 448 / 32 chunks

// ---- workspace layout (float offsets) ----
constexpr size_t WS_MU  = 0;        // [64]
constexpr size_t WS_RS  = 64;       // [64]
constexpr size_t WS_QSC = 128;      // [128]
constexpr size_t WS_QBI = 256;      // [128]
constexpr size_t WS_PSC = 384;      // [448]
constexpr size_t WS_PBI = 832;      // [448]
constexpr size_t WS_WG  = 1280;     // [128*96] (unused legacy slot)
constexpr size_t WS_SWG = 13568;    // [128]
constexpr size_t WS_WB  = 13696;    // [128]
constexpr size_t WS_WGT = 13824;    // [96*128] (unused legacy slot)
constexpr size_t WS_WGH = 26112;    // ushort[128][96] f16 Wg (6144 floats)
constexpr size_t WS_YB  = 32768;                                  // ushort[64][14][1024][32] chunked proj input
constexpr size_t WS_W16 = WS_YB + (size_t)BB*NPix*CDIM/2;         // ushort[512*448] bf16 proj W
constexpr size_t WS_QT  = WS_W16 + (size_t)512*CDIM/2;            // ushort f16 [64][1024][32]
constexpr size_t WS_KT  = WS_QT + (size_t)BB*NPix*32/2;           // ushort f16 [64][1024][32]
constexpr size_t WS_VB  = WS_KT + (size_t)BB*NPix*32/2;           // ushort f16 [64][96][1024]

typedef __attribute__((ext_vector_type(8))) short short8;
typedef __attribute__((ext_vector_type(8))) _Float16 half8;
typedef __attribute__((ext_vector_type(4))) float f32x4;

__device__ __forceinline__ unsigned short f2bf(float v) {
  __hip_bfloat16 h = __float2bfloat16(v);
  return *reinterpret_cast<unsigned short*>(&h);
}
__device__ __forceinline__ unsigned short f2h(float v) {
  _Float16 h = (_Float16)v;
  return *reinterpret_cast<unsigned short*>(&h);
}

typedef const __attribute__((address_space(1))) unsigned int* gp_t;
typedef __attribute__((address_space(3))) unsigned int* lp_t;
__device__ __forceinline__ void gload16(const void* g, void* l) {
  __builtin_amdgcn_global_load_lds((gp_t)g, (lp_t)l, 16, 0, 0);
}

// ---------------- kernel 1: fused setup + x2 passthrough (chunked full-line) --------
// Low-parallelism tail blocks dispatch FIRST (blocks 0..208) so they overlap
// the 11264-block XT phase instead of running serially after it.
constexpr int XT_BLOCKS = 11264;
constexpr int TAILB     = 209;
__global__ __launch_bounds__(256) void k_setup(
    const float* __restrict__ x,
    const float* __restrict__ gn_w, const float* __restrict__ gn_b,
    const float* __restrict__ qkv_w,
    const float* __restrict__ qbw, const float* __restrict__ qbb,
    const float* __restrict__ qbrm, const float* __restrict__ qbrv,
    const float* __restrict__ pw,
    const float* __restrict__ pbw, const float* __restrict__ pbb,
    const float* __restrict__ pbrm, const float* __restrict__ pbrv,
    float* __restrict__ ws, unsigned short* __restrict__ Wb,
    unsigned short* __restrict__ Ybc) {
  __shared__ float tile[32][65];   // 8.3 KB; also covers red[8]
  float* red = &tile[0][0];
  int t = threadIdx.x;
  if (blockIdx.x >= TAILB) {
    int idx = blockIdx.x - TAILB;
    int nx = idx & 15, cy = (idx >> 4) % 11, b = idx / 176;
    int c0 = PD + cy * 32;
    int n0 = nx * 64;
#pragma unroll
    for (int i = 0; i < 2; ++i) {
      int k = t + i * 256;
      int c = k >> 4, q = k & 15;
      float4 v = reinterpret_cast<const float4*>(
                     x + ((size_t)b * CDIM + c0 + c) * NPix + n0)[q];
      *reinterpret_cast<float4*>(&tile[c][q * 4]) = v;
    }
    __syncthreads();
    int n = t >> 2, ch = t & 3;
    short8 o;
#pragma unroll
    for (int j = 0; j < 8; ++j)
      o[j] = (short)f2bf(fmaxf(tile[ch * 8 + j][n], 0.f));
    *reinterpret_cast<short8*>(
        &Ybc[(((size_t)b * NCH + 3 + cy) * NPix + n0 + n) * 32 + ch * 8]) = o;
    return;
  }
  int bid = blockIdx.x;
  if (bid < 64) {
    int b = bid;
    const float4* x4 = reinterpret_cast<const float4*>(x + (size_t)b * CDIM * NPix);
    float s = 0.f, ss = 0.f;
#pragma unroll 8
    for (int ii = 0; ii < PD * NPix / 4 / 256; ++ii) {
      float4 v = x4[t + ii * 256];
      s  += v.x + v.y + v.z + v.w;
      ss += v.x * v.x + v.y * v.y + v.z * v.z + v.w * v.w;
    }
#pragma unroll
    for (int o = 32; o > 0; o >>= 1) { s += __shfl_down(s, o); ss += __shfl_down(ss, o); }
    int wid = t >> 6;
    if ((t & 63) == 0) { red[wid] = s; red[4 + wid] = ss; }
    __syncthreads();
    if (t == 0) {
      float S  = red[0] + red[1] + red[2] + red[3];
      float SS = red[4] + red[5] + red[6] + red[7];
      const float inv_n = 1.f / (PD * NPix);
      float mu  = S * inv_n;
      float var = SS * inv_n - mu * mu;
      ws[WS_MU + b] = mu;
      ws[WS_RS + b] = rsqrtf(var + EPS);
    }
  } else if (bid < 96) {
    // fold: one wave per output row o, lanes parallel over c (coalesced)
    int o = (bid - 64) * 4 + (t >> 6);
    int lane = t & 63;
    unsigned short* Wgh = reinterpret_cast<unsigned short*>(ws + WS_WGH);
    float sw = 0.f, bb = 0.f;
    for (int c = lane; c < PD; c += 64) {
      float w  = qkv_w[o * PD + c];
      float wg = w * gn_w[c];
      Wgh[(size_t)o * PD + c] = f2h(wg);
      sw += wg;
      bb += w * gn_b[c];
    }
#pragma unroll
    for (int off = 32; off > 0; off >>= 1) {
      sw += __shfl_down(sw, off);
      bb += __shfl_down(bb, off);
    }
    if (lane == 0) {
      ws[WS_SWG + o] = sw;
      ws[WS_WB + o]  = bb;
      float sc = qbw[o] * rsqrtf(qbrv[o] + EPS);
      ws[WS_QSC + o] = sc;
      ws[WS_QBI + o] = qbb[o] - qbrm[o] * sc;
    }
  } else if (bid == 96) {
    for (int o = t; o < CDIM; o += 256) {
      float sc = pbw[o] * rsqrtf(pbrv[o] + EPS);
      ws[WS_PSC + o] = sc;
      ws[WS_PBI + o] = pbb[o] - pbrm[o] * sc;
    }
  } else {
    int idx = (bid - 97) * 256 + t;   // 512*448/8 = 28672 chunks
    int row = idx / 56, sl = (idx % 56) * 8;
    short8 o = {};
    if (row < CDIM) {
      const float* src = pw + (size_t)row * CDIM + sl;
#pragma unroll
      for (int j = 0; j < 8; ++j) o[j] = (short)f2bf(src[j]);
    }
    *reinterpret_cast<short8*>(&Wb[(size_t)row * CDIM + sl]) = o;
  }
}

// ---------------- kernel 2: qkv via f16 MFMA + BN + operand emit ----------------
__global__ __launch_bounds__(256) void k_qkv2(const float* __restrict__ x,
                                              float* __restrict__ ws,
                                              unsigned short* __restrict__ qt,
                                              unsigned short* __restrict__ kt,
                                              unsigned short* __restrict__ vb) {
  __shared__ __align__(16) char smem[PD * 132 * 4];     // 50688 B union
  float*          xt = reinterpret_cast<float*>(smem);          // [96][132] f32
  unsigned short* ld = reinterpret_cast<unsigned short*>(smem); // [128][136] f16

  int lin = blockIdx.x + 8 * blockIdx.y;          // 512 wgs, chunked XCD swizzle
  int swz = (lin & 7) * 64 + (lin >> 3);
  int n0  = (swz & 7) * 128;
  int b   = swz >> 3;
  int t   = threadIdx.x;
  int lane = t & 63, w = t >> 6;
  int lo = lane & 15, hi = lane >> 4;

  const float4* xb4 = reinterpret_cast<const float4*>(x + (size_t)b * CDIM * NPix);
#pragma unroll
  for (int i = 0; i < 12; ++i) {                  // stage x1 tile [96][128]
    int idx = t + i * 256;
    int row = idx >> 5, c4 = idx & 31;
    float4 v = xb4[row * (NPix / 4) + (n0 >> 2) + c4];
    *reinterpret_cast<float4*>(&xt[row * 132 + c4 * 4]) = v;
  }
  __syncthreads();

  const unsigned short* Wgh = reinterpret_cast<const unsigned short*>(ws + WS_WGH);
  f32x4 acc[8][2] = {{{}}};
#pragma unroll
  for (int kk = 0; kk < 3; ++kk) {
    half8 bfr[2];
#pragma unroll
    for (int nf = 0; nf < 2; ++nf) {
      int nr = w * 32 + nf * 16 + lo;
      half8 h;
#pragma unroll
      for (int j = 0; j < 8; ++j)
        h[j] = (_Float16)xt[(kk * 32 + hi * 8 + j) * 132 + nr];
      bfr[nf] = h;
    }
#pragma unroll
    for (int of = 0; of < 8; ++of) {
      half8 a = *reinterpret_cast<const half8*>(
          &Wgh[(size_t)(of * 16 + lo) * PD + kk * 32 + hi * 8]);
      acc[of][0] = __builtin_amdgcn_mfma_f32_16x16x32_f16(a, bfr[0], acc[of][0], 0, 0, 0);
      acc[of][1] = __builtin_amdgcn_mfma_f32_16x16x32_f16(a, bfr[1], acc[of][1], 0, 0, 0);
    }
  }
  float mu = ws[WS_MU + b], rs = ws[WS_RS + b];
  __syncthreads();     // all xt reads done; smem becomes ld
#pragma unroll
  for (int of = 0; of < 8; ++of) {
#pragma unroll
    for (int r = 0; r < 4; ++r) {
      int o = of * 16 + hi * 4 + r;
      float bias = ws[WS_WB + o] - rs * mu * ws[WS_SWG + o];
      float qs = ws[WS_QSC + o], qb = ws[WS_QBI + o];
      float postm = (o < QKD) ? 0.25f : 1.f;
#pragma unroll
      for (int nf = 0; nf < 2; ++nf) {
        int nl = w * 32 + nf * 16 + lo;
        float v = (qs * (rs * acc[of][nf][r] + bias) + qb) * postm;
        ld[o * 136 + nl] = f2h(v);
      }
    }
  }
  __syncthreads();
  // ---- emit vb: rows o=32..127 -> c=0..95 ----
#pragma unroll
  for (int i = 0; i < 6; ++i) {
    int idx = t + i * 256;
    int row = idx >> 4, c8 = idx & 15;
    short8 v = *reinterpret_cast<const short8*>(&ld[(32 + row) * 136 + c8 * 8]);
    *reinterpret_cast<short8*>(&vb[((size_t)b * PD + row) * NPix + n0 + c8 * 8]) = v;
  }
  // ---- emit qt/kt: transposed gather, zero-padded to 32 ch ----
#pragma unroll
  for (int i = 0; i < 4; ++i) {
    int idx = t + i * 256;
    int arr = idx >> 9;
    int rem = idx & 511;
    int n = rem >> 2, q4 = rem & 3;
    short8 o = {};
    if (q4 < 2) {
#pragma unroll
      for (int j = 0; j < 8; ++j)
        o[j] = (short)ld[(arr * 16 + q4 * 8 + j) * 136 + n];
    }
    unsigned short* dst = arr ? kt : qt;
    *reinterpret_cast<short8*>(&dst[((size_t)b * NPix + n0 + n) * 32 + q4 * 8]) = o;
  }
}

// ---------------- kernel 3: flash attention via f16 MFMA -> Ybc chunks 0..2 ---------
__global__ __launch_bounds__(512) void k_attn2(
    const unsigned short* __restrict__ qt,
    const unsigned short* __restrict__ kt,
    const unsigned short* __restrict__ vb,
    unsigned short* __restrict__ Ybc) {
  __shared__ __align__(16) unsigned short kt_s[128 * 40];
  __shared__ __align__(16) unsigned short vt_s[96 * 136];
  __shared__ __align__(16) unsigned short P_s[8 * 16 * 136];

  int lin = blockIdx.x + 8 * blockIdx.y;
  int swz = (lin & 7) * 64 + (lin >> 3);
  int n0  = (swz & 7) * 128;
  int b   = swz >> 3;
  int t  = threadIdx.x;
  int lane = t & 63, w = t >> 6;
  int lo = lane & 15, hi = lane >> 4;

  half8 q8 = *reinterpret_cast<const half8*>(
      &qt[((size_t)b * NPix + n0 + w * 16 + lo) * 32 + hi * 8]);

  const unsigned short* ktb = kt + (size_t)b * NPix * 32;
  const unsigned short* vbb = vb + (size_t)b * PD * NPix;

  f32x4 o[6] = {};
  float M = -1e30f, L = 0.f;
  f32x4 zero = {};

  for (int mt = 0; mt < 8; ++mt) {
    int m0 = mt * 128;
    int krow = t >> 2, kc4 = t & 3;
    float4 rk = *reinterpret_cast<const float4*>(&ktb[(size_t)(m0 + krow) * 32 + kc4 * 8]);
    float4 rv[3];
#pragma unroll
    for (int i = 0; i < 3; ++i) {
      int ci = t + 512 * i;
      int row = ci >> 4, c4 = ci & 15;
      rv[i] = *reinterpret_cast<const float4*>(&vbb[(size_t)row * NPix + m0 + c4 * 8]);
    }
    __syncthreads();
    *reinterpret_cast<float4*>(&kt_s[krow * 40 + kc4 * 8]) = rk;
#pragma unroll
    for (int i = 0; i < 3; ++i) {
      int ci = t + 512 * i;
      int row = ci >> 4, c4 = ci & 15;
      *reinterpret_cast<float4*>(&vt_s[row * 136 + c4 * 8]) = rv[i];
    }
    __syncthreads();

    f32x4 s[8];
    __builtin_amdgcn_s_setprio(1);
#pragma unroll
    for (int ss = 0; ss < 8; ++ss) {
      half8 a = *reinterpret_cast<const half8*>(&kt_s[(ss * 16 + lo) * 40 + hi * 8]);
      s[ss] = __builtin_amdgcn_mfma_f32_16x16x32_f16(a, q8, zero, 0, 0, 0);
    }
    __builtin_amdgcn_s_setprio(0);

    float tmax = s[0][0];
#pragma unroll
    for (int ss = 0; ss < 8; ++ss)
#pragma unroll
      for (int r = 0; r < 4; ++r) tmax = fmaxf(tmax, s[ss][r]);
    tmax = fmaxf(tmax, __shfl_xor(tmax, 16));
    tmax = fmaxf(tmax, __shfl_xor(tmax, 32));
    float newM = fmaxf(M, tmax);
    float fac = __expf(M - newM);
    M = newM;
    float psum = 0.f;
    unsigned pbase = (w * 16 + lo) * 136;
#pragma unroll
    for (int ss = 0; ss < 8; ++ss) {
      float p0 = __expf(s[ss][0] - M);
      float p1 = __expf(s[ss][1] - M);
      float p2 = __expf(s[ss][2] - M);
      float p3 = __expf(s[ss][3] - M);
      psum += (p0 + p1) + (p2 + p3);
      unsigned u01 = (unsigned)f2h(p0) | ((unsigned)f2h(p1) << 16);
      unsigned u23 = (unsigned)f2h(p2) | ((unsigned)f2h(p3) << 16);
      *reinterpret_cast<unsigned*>(&P_s[pbase + 16 * ss + 4 * hi])     = u01;
      *reinterpret_cast<unsigned*>(&P_s[pbase + 16 * ss + 4 * hi + 2]) = u23;
    }
    psum += __shfl_xor(psum, 16);
    psum += __shfl_xor(psum, 32);
    L = L * fac + psum;
#pragma unroll
    for (int cf = 0; cf < 6; ++cf)
#pragma unroll
      for (int r = 0; r < 4; ++r) o[cf][r] *= fac;
    asm volatile("s_waitcnt lgkmcnt(0)" ::: "memory");

    __builtin_amdgcn_s_setprio(1);
#pragma unroll
    for (int ks = 0; ks < 4; ++ks) {
      half8 pb = *reinterpret_cast<const half8*>(&P_s[pbase + ks * 32 + hi * 8]);
#pragma unroll
      for (int cf = 0; cf < 6; ++cf) {
        half8 va = *reinterpret_cast<const half8*>(&vt_s[(cf * 16 + lo) * 136 + ks * 32 + hi * 8]);
        o[cf] = __builtin_amdgcn_mfma_f32_16x16x32_f16(va, pb, o[cf], 0, 0, 0);
      }
    }
    __builtin_amdgcn_s_setprio(0);
  }

  float inv = 1.f / L;
  unsigned pbase = (w * 16 + lo) * 136;
#pragma unroll
  for (int cf = 0; cf < 6; ++cf) {
    float v0 = fmaxf(o[cf][0] * inv, 0.f);
    float v1 = fmaxf(o[cf][1] * inv, 0.f);
    float v2 = fmaxf(o[cf][2] * inv, 0.f);
    float v3 = fmaxf(o[cf][3] * inv, 0.f);
    unsigned u01 = (unsigned)f2bf(v0) | ((unsigned)f2bf(v1) << 16);
    unsigned u23 = (unsigned)f2bf(v2) | ((unsigned)f2bf(v3) << 16);
    *reinterpret_cast<unsigned*>(&P_s[pbase + cf * 16 + 4 * hi])     = u01;
    *reinterpret_cast<unsigned*>(&P_s[pbase + cf * 16 + 4 * hi + 2]) = u23;
  }
  asm volatile("s_waitcnt lgkmcnt(0)" ::: "memory");
#pragma unroll
  for (int j = 0; j < 3; ++j) {
    int k = lane + 64 * j;
    int n = k / 12, c8 = k % 12;
    short8 vv = *reinterpret_cast<const short8*>(&P_s[(w * 16 + n) * 136 + c8 * 8]);
    *reinterpret_cast<short8*>(
        &Ybc[(((size_t)b * NCH + (c8 >> 2)) * NPix + n0 + w * 16 + n) * 32
             + (c8 & 3) * 8]) = vv;
  }
}

// ---------------- kernel 4: proj GEMM — A via 3-buf LDS, B direct global->reg ------
// B-frags are fragment-contiguous in Ybc by construction: 16B at
// [b][s][n0+br][hi*8]. Skip the LDS round-trip for B (halves LDS traffic,
// halves LDS footprint); register-prefetch B one K-step ahead.
__global__ __launch_bounds__(256) void k_projmm(
    const unsigned short* __restrict__ Wb,    // [512][448] bf16
    const unsigned short* __restrict__ Ybc,   // [64][14][1024][32] bf16
    const float* __restrict__ ws,
    float* __restrict__ out) {
  __shared__ __align__(16) unsigned short At[3][128 * 32];   // 24 KB total
  int lin = blockIdx.x + 8 * (blockIdx.y + 4 * blockIdx.z);  // 2048 wgs
  int swz = (lin & 7) * 256 + (lin >> 3);                    // chunked XCD swizzle
  int m0  = (swz & 3) * 128;         // m0 fastest: 4 m0-blocks of (b,n0) share XCD L2
  int n0  = ((swz >> 2) & 7) * 128;
  int b   = swz >> 5;
  int t  = threadIdx.x;
  int lane = t & 63, wid = t >> 6;
  int wm = wid >> 1, wn = wid & 1;
  int lo = lane & 15, hi = lane >> 4;

  const unsigned short* Arow = Wb + (size_t)m0 * CDIM;
  const unsigned short* Brow = Ybc + ((size_t)b * NCH * NPix + n0) * 32;

  int chunk0 = wid * 128 + lane;
  int row0 = chunk0 >> 2, sl0 = (chunk0 & 3) ^ ((row0 >> 1) & 3);
  int chunk1 = chunk0 + 64;
  int row1 = chunk1 >> 2, sl1 = (chunk1 & 3) ^ ((row1 >> 1) & 3);

#define STAGE_A(bufi, s_)                                                      \
  do {                                                                         \
    gload16(Arow + (size_t)row0 * CDIM + (s_) * 32 + sl0 * 8,                  \
            &At[bufi][(wid * 128) * 8]);                                       \
    gload16(Arow + (size_t)row1 * CDIM + (s_) * 32 + sl1 * 8,                  \
            &At[bufi][(wid * 128 + 64) * 8]);                                  \
  } while (0)

#define LOADB(dst, s_)                                                         \
  do {                                                                         \
    _Pragma("unroll")                                                          \
    for (int f = 0; f < 4; ++f)                                                \
      dst[f] = *reinterpret_cast<const short8*>(                               \
          &Brow[(size_t)(s_) * NPix * 32 + (wn * 64 + f * 16 + lo) * 32 +      \
                hi * 8]);                                                      \
  } while (0)

  f32x4 acc[4][4] = {{{}}};
  short8 bcur[4], bnxt[4];

  STAGE_A(0, 0);
  STAGE_A(1, 1);
  LOADB(bcur, 0);
  // oldest = A(0) 2 loads; younger = A(1) 2 + B(0) 4 = 6
  asm volatile("s_waitcnt vmcnt(6)" ::: "memory");
  __builtin_amdgcn_sched_barrier(0);
  __builtin_amdgcn_s_barrier();

#pragma unroll
  for (int s = 0; s < 14; ++s) {
    if (s + 2 <= 13) STAGE_A((s + 2) % 3, s + 2);
    if (s + 1 <= 13) LOADB(bnxt, s + 1);
    short8 af[4];
#pragma unroll
    for (int f = 0; f < 4; ++f) {
      int ar = wm * 64 + f * 16 + lo;
      int as = hi ^ ((ar >> 1) & 3);
      af[f] = *reinterpret_cast<const short8*>(&At[s % 3][ar * 32 + as * 8]);
    }
#pragma unroll
    for (int i = 0; i < 4; ++i)
#pragma unroll
      for (int j = 0; j < 4; ++j)
        acc[i][j] = __builtin_amdgcn_mfma_f32_16x16x32_bf16(af[i], bcur[j], acc[i][j], 0, 0, 0);
#pragma unroll
    for (int f = 0; f < 4; ++f) bcur[f] = bnxt[f];
    if (s < 13) {
      // need A(s+1) drained before next step's ds_read; younger in flight:
      // A(s+2) (2, if any) + B(s+1) (4)
      if (s <= 11) asm volatile("s_waitcnt vmcnt(6) lgkmcnt(0)" ::: "memory");
      else         asm volatile("s_waitcnt vmcnt(4) lgkmcnt(0)" ::: "memory");
      __builtin_amdgcn_sched_barrier(0);
      __builtin_amdgcn_s_barrier();
    }
  }
#undef STAGE_A
#undef LOADB

  int col = lane & 15, rq = lane >> 4;
#pragma unroll
  for (int i = 0; i < 4; ++i) {
    int ob = m0 + wm * 64 + i * 16 + rq * 4;
#pragma unroll
    for (int r = 0; r < 4; ++r) {
      int o = ob + r;
      if (o < CDIM) {
        float ps = ws[WS_PSC + o], pb = ws[WS_PBI + o];
        size_t base = ((size_t)b * CDIM + o) * NPix + n0 + wn * 64 + col;
#pragma unroll
        for (int j = 0; j < 4; ++j)
          out[base + j * 16] = ps * acc[i][j][r] + pb;
      }
    }
  }
}

extern "C" void kernel_launch(void* const* d_in, const int* in_sizes, int n_in,
                              void* d_out, int out_size, void* d_ws, size_t ws_size,
                              hipStream_t stream) {
  const float* x      = (const float*)d_in[0];
  const float* gn_w   = (const float*)d_in[1];
  const float* gn_b   = (const float*)d_in[2];
  const float* qkv_w  = (const float*)d_in[3];
  const float* qbw    = (const float*)d_in[4];
  const float* qbb    = (const float*)d_in[5];
  const float* qbrm   = (const float*)d_in[6];
  const float* qbrv   = (const float*)d_in[7];
  const float* pw     = (const float*)d_in[8];
  const float* pbw    = (const float*)d_in[9];
  const float* pbb    = (const float*)d_in[10];
  const float* pbrm   = (const float*)d_in[11];
  const float* pbrv   = (const float*)d_in[12];
  float* out = (float*)d_out;
  float* ws  = (float*)d_ws;
  unsigned short* Ybc = (unsigned short*)(ws + WS_YB);
  unsigned short* Wb  = (unsigned short*)(ws + WS_W16);
  unsigned short* qt  = (unsigned short*)(ws + WS_QT);
  unsigned short* kt  = (unsigned short*)(ws + WS_KT);
  unsigned short* vb  = (unsigned short*)(ws + WS_VB);

  k_setup<<<TAILB + XT_BLOCKS, 256, 0, stream>>>(
      x, gn_w, gn_b, qkv_w, qbw, qbb, qbrm, qbrv,
      pw, pbw, pbb, pbrm, pbrv, ws, Wb, Ybc);
  k_qkv2<<<dim3(8, BB), 256, 0, stream>>>(x, ws, qt, kt, vb);
  k_attn2<<<dim3(8, BB), 512, 0, stream>>>(qt, kt, vb, Ybc);
  k_projmm<<<dim3(8, 4, BB), 256, 0, stream>>>(Wb, Ybc, ws, out);
}